// Round 1
// baseline (3751.562 us; speedup 1.0000x reference)
//
#include <hip/hip_runtime.h>

// Problem constants
#define NB   2048   // batch
#define SEQ  168    // encoder steps
#define NF   7      // features
#define NH   128    // hidden
#define G4   512    // 4*NH gate rows
#define NP   96     // decoder steps
#define ROWS 8      // batch rows per block
#define NTHR 512

typedef _Float16 h16;
typedef _Float16 h16x2 __attribute__((ext_vector_type(2)));

// -------- d_ws layout (bytes). Total needed ~88.6 MB. --------
constexpr size_t WT_ENC_OFF = 0;                 // h16[32][512][4]  (W_hh_enc^T, k-packed by 4)
constexpr size_t WT_DEC_OFF = 131072;            // h16[64][512][4]  (concat[W_ih_dec,W_hh_dec]^T)
constexpr size_t WATT_OFF   = 131072 + 262144;   // 393216: h16[168][136] (W_att rows, padded 135->136)
constexpr size_t BENC_OFF   = 458752;            // f32[512] b_ih_enc+b_hh_enc
constexpr size_t BDEC_OFF   = 460800;            // f32[512] b_ih_dec+b_hh_dec
constexpr size_t ENC_OFF    = 524288;            // h16[NB*SEQ*NH] encoder outputs (88.1 MB)

#if __has_builtin(__builtin_amdgcn_fdot2)
__device__ __forceinline__ float fdot2f(h16x2 a, h16x2 b, float c) {
  return __builtin_amdgcn_fdot2(a, b, c, false);
}
#else
__device__ __forceinline__ float fdot2f(h16x2 a, h16x2 b, float c) {
  return c + (float)a.x * (float)b.x + (float)a.y * (float)b.y;
}
#endif

__device__ __forceinline__ h16x2 bc2(unsigned int u) { return __builtin_bit_cast(h16x2, u); }
__device__ __forceinline__ float sigm(float x) { return 1.f / (1.f + __expf(-x)); }
__device__ __forceinline__ float tanh_(float x) {
  // overflow-safe tanh: e <= 1 always
  float e = __expf(-2.f * fabsf(x));
  return copysignf((1.f - e) / (1.f + e), x);
}

// -------- setup: transpose/cast weights into ws (re-run every launch; ws is re-poisoned) --------
__global__ void setup_weights(const float* __restrict__ Whh_enc, const float* __restrict__ Wih_dec,
                              const float* __restrict__ Whh_dec, const float* __restrict__ Watt,
                              const float* __restrict__ bihe, const float* __restrict__ bhhe,
                              const float* __restrict__ bihd, const float* __restrict__ bhhd,
                              char* __restrict__ ws) {
  int idx = blockIdx.x * blockDim.x + threadIdx.x;
  if (idx < 65536) {
    // enc: [kq<32][g<512][e<4] <- W_hh_enc[g][kq*4+e]
    int e = idx & 3, g = (idx >> 2) & 511, kq = idx >> 11;
    ((h16*)(ws + WT_ENC_OFF))[idx] = (h16)Whh_enc[g * NH + kq * 4 + e];
  } else if (idx < 65536 + 131072) {
    // dec: [kq<64][g<512][e<4]; k<128 -> W_ih_dec (combine), k>=128 -> W_hh_dec (prev_h)
    int i = idx - 65536;
    int e = i & 3, g = (i >> 2) & 511, kq = i >> 11;
    int k = kq * 4 + e;
    float v = (k < NH) ? Wih_dec[g * NH + k] : Whh_dec[g * NH + (k - NH)];
    ((h16*)(ws + WT_DEC_OFF))[i] = (h16)v;
  } else if (idx < 65536 + 131072 + 22848) {
    // att: [s<168][j<136], pad j=135 with 0
    int i = idx - (65536 + 131072);
    int j = i % 136, s = i / 136;
    float v = (j < NH + NF) ? Watt[s * (NH + NF) + j] : 0.f;
    ((h16*)(ws + WATT_OFF))[i] = (h16)v;
  } else if (idx < 65536 + 131072 + 22848 + 512) {
    int g = idx - (65536 + 131072 + 22848);
    ((float*)(ws + BENC_OFF))[g] = bihe[g] + bhhe[g];
    ((float*)(ws + BDEC_OFF))[g] = bihd[g] + bhhd[g];
  }
}

// -------- main persistent kernel: each block owns 8 batch rows, runs all 168+96 steps --------
__global__ __launch_bounds__(NTHR)
void encdec_kernel(const float* __restrict__ xb, const float* __restrict__ Wih_enc,
                   const float* __restrict__ b_att, const float* __restrict__ Wout,
                   const float* __restrict__ bout, const float* __restrict__ Wfin,
                   const float* __restrict__ bfin, char* __restrict__ ws,
                   float* __restrict__ out) {
  __shared__ alignas(16) h16   sh_x[ROWS][SEQ][8];    // xb slice, f16, padded F->8   21504 B
  __shared__ alignas(16) h16   sh_hh[ROWS][NH];       // encoder h (f16 for dots)      2048 B
  __shared__ alignas(16) float sh_c[ROWS][NH];        // encoder c (fp32)              4096 B
  __shared__ alignas(16) float sh_pre[ROWS][G4];      // gate pre-activations         16384 B
  __shared__ alignas(16) float sh_ph[ROWS][NH];       // fp32 h_T / decoder cell       4096 B
  __shared__ alignas(16) h16   sh_ainh[ROWS][136];    // attn_in = [c(128), y(7), 0]   2176 B
  __shared__ alignas(16) h16   sh_cath[ROWS][256];    // [combine(128), prev_h(128)]   4096 B
  __shared__ alignas(16) float sh_attw[ROWS][SEQ];    // logits -> softmax weights     5376 B
  __shared__ alignas(16) float sh_out[ROWS][8];       // decoder out (F=7)              256 B

  const int t  = threadIdx.x;
  const int r0 = blockIdx.x * ROWS;

  const h16*   __restrict__ wt_enc = (const h16*)(ws + WT_ENC_OFF);
  const h16*   __restrict__ wt_dec = (const h16*)(ws + WT_DEC_OFF);
  const h16*   __restrict__ watt   = (const h16*)(ws + WATT_OFF);
  const float* __restrict__ benc_p = (const float*)(ws + BENC_OFF);
  const float* __restrict__ bdec_p = (const float*)(ws + BDEC_OFF);
  h16*         __restrict__ encg   = (h16*)(ws + ENC_OFF);

  // stage xb slice (f16, pad f=7 with 0 to avoid NaN from poison)
  for (int i = t; i < ROWS * SEQ * 8; i += NTHR) {
    int r = i / (SEQ * 8);
    int rem = i - r * (SEQ * 8);
    int s = rem >> 3, f = rem & 7;
    float v = (f < NF) ? xb[((size_t)(r0 + r) * SEQ + s) * NF + f] : 0.f;
    sh_x[r][s][f] = (h16)v;
  }
  for (int i = t; i < ROWS * NH; i += NTHR) {
    int r = i >> 7, k = i & 127;
    sh_hh[r][k] = (h16)0.f;
    sh_c[r][k] = 0.f;
  }

  // per-thread regs: thread t == gate row g for E1/D4
  h16 wtmp[8];
  #pragma unroll
  for (int f = 0; f < 8; ++f) wtmp[f] = (f < NF) ? (h16)Wih_enc[t * NF + f] : (h16)0.f;
  const h16x2 wih0 = {wtmp[0], wtmp[1]};
  const h16x2 wih1 = {wtmp[2], wtmp[3]};
  const h16x2 wih2 = {wtmp[4], wtmp[5]};
  const h16x2 wih3 = {wtmp[6], wtmp[7]};
  const float benc = benc_p[t];
  const float bdec = bdec_p[t];

  const int hh = t & 127;   // elementwise mapping: 4 groups x 2 rows
  const int rq = t >> 7;

  __syncthreads();

  // ================= encoder: 168 steps =================
  for (int s = 0; s < SEQ; ++s) {
    // E1: pre[r][t] = b_enc + x_ih + h @ W_hh^T   (thread t = gate row)
    float acc[ROWS];
    #pragma unroll
    for (int r = 0; r < ROWS; ++r) {
      float a = benc;
      uint4 xv = *(const uint4*)&sh_x[r][s][0];
      a = fdot2f(bc2(xv.x), wih0, a);
      a = fdot2f(bc2(xv.y), wih1, a);
      a = fdot2f(bc2(xv.z), wih2, a);
      a = fdot2f(bc2(xv.w), wih3, a);
      acc[r] = a;
    }
    #pragma unroll 4
    for (int kq = 0; kq < 32; ++kq) {
      uint2 wv = *(const uint2*)(wt_enc + (size_t)(kq * G4 + t) * 4);  // coalesced 256B/wave
      h16x2 w0 = bc2(wv.x), w1 = bc2(wv.y);
      #pragma unroll
      for (int r = 0; r < ROWS; ++r) {
        uint2 hv = *(const uint2*)&sh_hh[r][kq * 4];  // LDS broadcast
        acc[r] = fdot2f(bc2(hv.x), w0, acc[r]);
        acc[r] = fdot2f(bc2(hv.y), w1, acc[r]);
      }
    }
    #pragma unroll
    for (int r = 0; r < ROWS; ++r) sh_pre[r][t] = acc[r];
    __syncthreads();

    // E2: elementwise LSTM cell, write h to LDS + global enc history (f16)
    #pragma unroll
    for (int rr = 0; rr < 2; ++rr) {
      int r = rq * 2 + rr;
      float gi = sigm(sh_pre[r][hh]);
      float gf = sigm(sh_pre[r][hh + 128]);
      float gg = tanh_(sh_pre[r][hh + 256]);
      float go = sigm(sh_pre[r][hh + 384]);
      float c = gf * sh_c[r][hh] + gi * gg;
      float h = go * tanh_(c);
      sh_c[r][hh] = c;
      sh_hh[r][hh] = (h16)h;
      sh_ph[r][hh] = h;  // fp32 copy (decoder needs fp32 h_T at init)
      encg[((size_t)(r0 + r) * SEQ + s) * NH + hh] = (h16)h;
    }
    __syncthreads();
  }

  // ================= decoder init =================
  #pragma unroll
  for (int rr = 0; rr < 2; ++rr) {
    int r = rq * 2 + rr;
    h16 hv = sh_hh[r][hh];
    sh_cath[r][128 + hh] = hv;  // prev_h half for gate dot
    sh_ainh[r][hh] = hv;        // attn_in h-part
  }
  if (t < 56) {
    int r = t / 7, f = t - (t / 7) * 7;
    sh_ainh[r][128 + f] = sh_x[r][SEQ - 1][f];  // y0 = xb[:, -1, :]
  }
  if (t < ROWS) sh_ainh[t][135] = (h16)0.f;  // pad
  __syncthreads();

  // per-thread decoder constants
  const int ss = t % 168;            // D1: attention column s
  const int rh = t / 168;            //     row-half (4 rows each)
  const float batt = (t < 336) ? b_att[ss] : 0.f;
  const int sl = t & 31;             // D2 softmax lane
  const int sr = t >> 5;             //     softmax row
  const int h2i = t & 63;            // D3 h-pair
  const int cr = t >> 6;             //     row
  const int orow = t / 7;            // D6 mapping
  const int ocol = t - (t / 7) * 7;

  // ================= decoder: 96 steps =================
  for (int p = 0; p < NP; ++p) {
    // D1: logits[r][s] = attn_in . W_att[s] + b_att[s]
    if (t < 336) {
      float a0 = batt, a1 = batt, a2 = batt, a3 = batt;
      const h16* war = watt + ss * 136;
      #pragma unroll 2
      for (int jq = 0; jq < 34; ++jq) {
        uint2 wv = *(const uint2*)(war + jq * 4);
        h16x2 w0 = bc2(wv.x), w1 = bc2(wv.y);
        uint2 v0 = *(const uint2*)&sh_ainh[rh * 4 + 0][jq * 4];
        uint2 v1 = *(const uint2*)&sh_ainh[rh * 4 + 1][jq * 4];
        uint2 v2 = *(const uint2*)&sh_ainh[rh * 4 + 2][jq * 4];
        uint2 v3 = *(const uint2*)&sh_ainh[rh * 4 + 3][jq * 4];
        a0 = fdot2f(bc2(v0.x), w0, a0); a0 = fdot2f(bc2(v0.y), w1, a0);
        a1 = fdot2f(bc2(v1.x), w0, a1); a1 = fdot2f(bc2(v1.y), w1, a1);
        a2 = fdot2f(bc2(v2.x), w0, a2); a2 = fdot2f(bc2(v2.y), w1, a2);
        a3 = fdot2f(bc2(v3.x), w0, a3); a3 = fdot2f(bc2(v3.y), w1, a3);
      }
      sh_attw[rh * 4 + 0][ss] = a0;
      sh_attw[rh * 4 + 1][ss] = a1;
      sh_attw[rh * 4 + 2][ss] = a2;
      sh_attw[rh * 4 + 3][ss] = a3;
    }
    __syncthreads();

    // D2: softmax over s (32 lanes per row, shuffle reduce)
    if (t < 256) {
      float vals[6];
      float m = -1e30f;
      #pragma unroll
      for (int j = 0; j < 6; ++j) {
        int s = sl + 32 * j;
        vals[j] = (s < SEQ) ? sh_attw[sr][s] : -1e30f;
        m = fmaxf(m, vals[j]);
      }
      #pragma unroll
      for (int off = 16; off > 0; off >>= 1) m = fmaxf(m, __shfl_xor(m, off, 32));
      float sum = 0.f;
      #pragma unroll
      for (int j = 0; j < 6; ++j) {
        float e = __expf(vals[j] - m);
        e = (sl + 32 * j < SEQ) ? e : 0.f;
        vals[j] = e;
        sum += e;
      }
      #pragma unroll
      for (int off = 16; off > 0; off >>= 1) sum += __shfl_xor(sum, off, 32);
      float inv = 1.f / sum;
      #pragma unroll
      for (int j = 0; j < 6; ++j) {
        int s = sl + 32 * j;
        if (s < SEQ) sh_attw[sr][s] = vals[j] * inv;
      }
    }
    __syncthreads();

    // D3: combine[r][h] = sum_s w[r][s] * enc[r][s][h]  (coalesced f16 pair reads)
    {
      const h16* er = encg + ((size_t)(r0 + cr) * SEQ) * NH + 2 * h2i;
      float ax = 0.f, ay = 0.f;
      #pragma unroll 4
      for (int s = 0; s < SEQ; ++s) {
        float w = sh_attw[cr][s];
        h16x2 e2 = *(const h16x2*)(er + (size_t)s * NH);
        ax += w * (float)e2.x;
        ay += w * (float)e2.y;
      }
      sh_cath[cr][2 * h2i]     = (h16)ax;
      sh_cath[cr][2 * h2i + 1] = (h16)ay;
    }
    __syncthreads();

    // D4: gates = [combine, prev_h] @ [W_ih_dec, W_hh_dec]^T + b_dec   (thread t = gate row)
    {
      float acc[ROWS];
      #pragma unroll
      for (int r = 0; r < ROWS; ++r) acc[r] = bdec;
      #pragma unroll 4
      for (int kq = 0; kq < 64; ++kq) {
        uint2 wv = *(const uint2*)(wt_dec + (size_t)(kq * G4 + t) * 4);  // coalesced
        h16x2 w0 = bc2(wv.x), w1 = bc2(wv.y);
        #pragma unroll
        for (int r = 0; r < ROWS; ++r) {
          uint2 cv = *(const uint2*)&sh_cath[r][kq * 4];  // LDS broadcast
          acc[r] = fdot2f(bc2(cv.x), w0, acc[r]);
          acc[r] = fdot2f(bc2(cv.y), w1, acc[r]);
        }
      }
      #pragma unroll
      for (int r = 0; r < ROWS; ++r) sh_pre[r][t] = acc[r];
    }
    __syncthreads();

    // D5: c_new = sigm(i)*tanh(g) + sigm(f)*prev_h   (o unused in decoder)
    #pragma unroll
    for (int rr = 0; rr < 2; ++rr) {
      int r = rq * 2 + rr;
      float gi = sigm(sh_pre[r][hh]);
      float gf = sigm(sh_pre[r][hh + 128]);
      float gg = tanh_(sh_pre[r][hh + 256]);
      float cn = gf * sh_ph[r][hh] + gi * gg;
      sh_ph[r][hh] = cn;
      h16 ch = (h16)cn;
      sh_cath[r][128 + hh] = ch;  // prev_h for next D4
      sh_ainh[r][hh] = ch;        // attn_in for next D1
    }
    __syncthreads();

    // D6: out[r][f] = c_new . W_out[f] + b_out[f]
    if (t < 56) {
      float a = bout[ocol];
      const float* wr = Wout + ocol * NH;
      #pragma unroll 8
      for (int k = 0; k < NH; k += 4) {
        float4 pv = *(const float4*)&sh_ph[orow][k];
        float4 wv = *(const float4*)(wr + k);
        a += pv.x * wv.x + pv.y * wv.y + pv.z * wv.z + pv.w * wv.w;
      }
      sh_out[orow][ocol] = a;
      sh_ainh[orow][128 + ocol] = (h16)a;  // y_prev for next D1
    }
    __syncthreads();

    // D7: final[b][p] = out . W_fin + b_fin  (no trailing barrier needed: next
    // conflicting write to sh_out is D6(p+1), separated by >=5 barriers)
    if (t < ROWS) {
      float a = bfin[0];
      #pragma unroll
      for (int f = 0; f < NF; ++f) a += sh_out[t][f] * Wfin[f];
      out[(size_t)(r0 + t) * NP + p] = a;
    }
  }
}

extern "C" void kernel_launch(void* const* d_in, const int* in_sizes, int n_in,
                              void* d_out, int out_size, void* d_ws, size_t ws_size,
                              hipStream_t stream) {
  const float* xb      = (const float*)d_in[0];
  const float* Wih_enc = (const float*)d_in[1];
  const float* Whh_enc = (const float*)d_in[2];
  const float* bih_enc = (const float*)d_in[3];
  const float* bhh_enc = (const float*)d_in[4];
  const float* Watt    = (const float*)d_in[5];
  const float* batt    = (const float*)d_in[6];
  const float* Wih_dec = (const float*)d_in[7];
  const float* Whh_dec = (const float*)d_in[8];
  const float* bih_dec = (const float*)d_in[9];
  const float* bhh_dec = (const float*)d_in[10];
  const float* Wout    = (const float*)d_in[11];
  const float* bout    = (const float*)d_in[12];
  const float* Wfin    = (const float*)d_in[13];
  const float* bfin    = (const float*)d_in[14];
  char* ws = (char*)d_ws;      // needs ~88.6 MB (enc history f16 + transposed weights)
  float* outp = (float*)d_out;

  // 65536 + 131072 + 22848 + 512 = 219968 elements
  setup_weights<<<860, 256, 0, stream>>>(Whh_enc, Wih_dec, Whh_dec, Watt,
                                         bih_enc, bhh_enc, bih_dec, bhh_dec, ws);
  encdec_kernel<<<NB / ROWS, NTHR, 0, stream>>>(xb, Wih_enc, batt, Wout, bout,
                                                Wfin, bfin, ws, outp);
}

// Round 2
// 2106.141 us; speedup vs baseline: 1.7812x; 1.7812x over previous
//
#include <hip/hip_runtime.h>

// Problem constants
#define NB   2048   // batch
#define SEQ  168    // encoder steps
#define NF   7      // features
#define NH   128    // hidden
#define G4   512    // 4*NH gate rows
#define NP   96     // decoder steps
#define ROWS 8      // batch rows per block (padded to M=16 for MFMA)
#define NTHR 512
#define KE   160    // enc A/B K: [x 0..6][pad 7][h 8..135][pad 136..159]
#define KD   256    // dec A/B K: [combine 0..127][prev_h 128..255]
#define HXS  168    // sh_hx row stride in h16 (336B -> 2-way banks on b128 frag reads)
#define CTS  264    // sh_cath row stride in h16 (528B -> 2-way)
#define PRS  513    // sh_pre row stride in f32 (conflict-free writeback/read)

typedef _Float16 h16;
typedef _Float16 h16x2 __attribute__((ext_vector_type(2)));
typedef _Float16 h16x8 __attribute__((ext_vector_type(8)));
typedef float    f32x4 __attribute__((ext_vector_type(4)));

// -------- d_ws layout (bytes). Total ~88.6 MB. --------
constexpr size_t WENC_OFF = 0;        // h16[512][160]  W_enc rows: [Wih(7)|0|Whh(128)|0...]
constexpr size_t WDEC_OFF = 163840;   // h16[512][256]  [Wih_dec(128)|Whh_dec(128)]
constexpr size_t WATT_OFF = 425984;   // h16[168][136]
constexpr size_t BENC_OFF = 471680;   // f32[512]
constexpr size_t BDEC_OFF = 473728;   // f32[512]
constexpr size_t ENC_OFF  = 524288;   // h16[NB*SEQ*NH] encoder outputs (88.1 MB)

#if __has_builtin(__builtin_amdgcn_fdot2)
__device__ __forceinline__ float fdot2f(h16x2 a, h16x2 b, float c) {
  return __builtin_amdgcn_fdot2(a, b, c, false);
}
#else
__device__ __forceinline__ float fdot2f(h16x2 a, h16x2 b, float c) {
  return c + (float)a.x * (float)b.x + (float)a.y * (float)b.y;
}
#endif

__device__ __forceinline__ h16x2 bc2(unsigned int u) { return __builtin_bit_cast(h16x2, u); }
__device__ __forceinline__ float sigm(float x) { return 1.f / (1.f + __expf(-x)); }
__device__ __forceinline__ float tanh_(float x) {
  float e = __expf(-2.f * fabsf(x));
  return copysignf((1.f - e) / (1.f + e), x);
}

// -------- setup: cast/pack weights into ws (re-run every launch; ws re-poisoned) --------
__global__ void setup_weights(const float* __restrict__ Wih_enc, const float* __restrict__ Whh_enc,
                              const float* __restrict__ Wih_dec, const float* __restrict__ Whh_dec,
                              const float* __restrict__ Watt,
                              const float* __restrict__ bihe, const float* __restrict__ bhhe,
                              const float* __restrict__ bihd, const float* __restrict__ bhhd,
                              char* __restrict__ ws) {
  int idx = blockIdx.x * blockDim.x + threadIdx.x;
  if (idx < 81920) {
    // enc B: row n, k<7 -> Wih[n][k]; 8<=k<136 -> Whh[n][k-8]; else 0
    int n = idx / KE, k = idx % KE;
    float v = 0.f;
    if (k < NF) v = Wih_enc[n * NF + k];
    else if (k >= 8 && k < 136) v = Whh_enc[n * NH + (k - 8)];
    ((h16*)(ws + WENC_OFF))[idx] = (h16)v;
  } else if (idx < 81920 + 131072) {
    int i = idx - 81920;
    int n = i / KD, k = i % KD;
    float v = (k < NH) ? Wih_dec[n * NH + k] : Whh_dec[n * NH + (k - NH)];
    ((h16*)(ws + WDEC_OFF))[i] = (h16)v;
  } else if (idx < 81920 + 131072 + 22848) {
    int i = idx - (81920 + 131072);
    int j = i % 136, s = i / 136;
    float v = (j < NH + NF) ? Watt[s * (NH + NF) + j] : 0.f;
    ((h16*)(ws + WATT_OFF))[i] = (h16)v;
  } else if (idx < 81920 + 131072 + 22848 + 512) {
    int g = idx - (81920 + 131072 + 22848);
    ((float*)(ws + BENC_OFF))[g] = bihe[g] + bhhe[g];
    ((float*)(ws + BDEC_OFF))[g] = bihd[g] + bhhd[g];
  }
}

// -------- main persistent kernel: 8 batch rows/block, all 168+96 steps, MFMA gate GEMMs --------
__global__ __launch_bounds__(NTHR, 2)
void encdec_kernel(const float* __restrict__ xb, const float* __restrict__ b_att,
                   const float* __restrict__ Wout, const float* __restrict__ bout,
                   const float* __restrict__ Wfin, const float* __restrict__ bfin,
                   const h16* __restrict__ w16enc, const h16* __restrict__ w16dec,
                   const h16* __restrict__ watt, const float* __restrict__ bencp,
                   const float* __restrict__ bdecp, h16* __restrict__ encg,
                   float* __restrict__ out) {
  __shared__ alignas(16) h16   sh_hx[16][HXS];      // MFMA A (enc): [x|0|h|0], rows 8-15 zero  5376 B
  __shared__ alignas(16) float sh_c[ROWS][NH];      // encoder c                                4096 B
  __shared__ alignas(16) float sh_pre[ROWS][PRS];   // gate pre-activations                    16416 B
  __shared__ alignas(16) float sh_ph[ROWS][NH];     // fp32 h_T / decoder cell                  4096 B
  __shared__ alignas(16) h16   sh_ainh[ROWS][136];  // attn_in = [h(128), y(7), 0]              2176 B
  __shared__ alignas(16) h16   sh_cath[16][CTS];    // MFMA A (dec): [combine|prev_h]           8448 B
  __shared__ alignas(16) float sh_attw[ROWS][SEQ];  // logits -> softmax weights                5376 B
  __shared__ alignas(16) float sh_out[ROWS][8];     // decoder out (F=7)                         256 B

  const int t  = threadIdx.x;
  const int r0 = blockIdx.x * ROWS;

  // init LDS (no sh_x: xb read directly)
  for (int i = t; i < 16 * HXS; i += NTHR) {
    int r = i / HXS, k = i % HXS;
    float v = 0.f;
    if (r < ROWS && k < NF) v = xb[((size_t)(r0 + r) * SEQ + 0) * NF + k];
    sh_hx[r][k] = (h16)v;
  }
  for (int i = t; i < ROWS * NH; i += NTHR) { int r = i >> 7, k = i & 127; sh_c[r][k] = 0.f; }
  for (int i = t; i < 8 * CTS; i += NTHR)  { int r = i / CTS, k = i % CTS; sh_cath[8 + r][k] = (h16)0.f; }

  // wave/lane decomposition for MFMA
  const int w  = t >> 6;   // wave id: owns gate slice n in [w*64, w*64+64)
  const int l  = t & 63;
  const int lq = l >> 4;   // quad
  const int ln = l & 15;

  // preload enc B fragments (step-invariant weights -> VGPRs)
  h16x8 bfE[4][5];
  float bE[4];
  #pragma unroll
  for (int nt = 0; nt < 4; ++nt) {
    int n = w * 64 + nt * 16 + ln;
    bE[nt] = bencp[n];
    #pragma unroll
    for (int kt = 0; kt < 5; ++kt)
      bfE[nt][kt] = *(const h16x8*)(w16enc + n * KE + kt * 32 + lq * 8);
  }

  const int hh = t & 127;  // elementwise mapping
  const int rq = t >> 7;

  __syncthreads();

  // ================= encoder: 168 steps =================
  for (int s = 0; s < SEQ; ++s) {
    // prefetch next-step x (overlaps E1)
    float xnext[2];
    #pragma unroll
    for (int rr = 0; rr < 2; ++rr) {
      int r = rq * 2 + rr;
      xnext[rr] = (hh < NF && s + 1 < SEQ) ? xb[((size_t)(r0 + r) * SEQ + s + 1) * NF + hh] : 0.f;
    }

    // E1: pre = [x|h] @ W_enc^T via MFMA (M=16 batch, N=512 gates, K=160)
    {
      h16x8 af[5];
      #pragma unroll
      for (int kt = 0; kt < 5; ++kt)
        af[kt] = *(const h16x8*)(&sh_hx[ln][kt * 32 + lq * 8]);
      #pragma unroll
      for (int nt = 0; nt < 4; ++nt) {
        f32x4 acc = {0.f, 0.f, 0.f, 0.f};
        #pragma unroll
        for (int kt = 0; kt < 5; ++kt)
          acc = __builtin_amdgcn_mfma_f32_16x16x32_f16(af[kt], bfE[nt][kt], acc, 0, 0, 0);
        int n = w * 64 + nt * 16 + ln;
        #pragma unroll
        for (int reg = 0; reg < 4; ++reg) {
          int m = lq * 4 + reg;   // C layout: col=lane&15 (n), row=quad*4+reg (m)
          if (m < ROWS) sh_pre[m][n] = acc[reg] + bE[nt];
        }
      }
    }
    __syncthreads();

    // E2: LSTM cell elementwise
    #pragma unroll
    for (int rr = 0; rr < 2; ++rr) {
      int r = rq * 2 + rr;
      float gi = sigm(sh_pre[r][hh]);
      float gf = sigm(sh_pre[r][hh + 128]);
      float gg = tanh_(sh_pre[r][hh + 256]);
      float go = sigm(sh_pre[r][hh + 384]);
      float c = gf * sh_c[r][hh] + gi * gg;
      float h = go * tanh_(c);
      sh_c[r][hh] = c;
      sh_hx[r][8 + hh] = (h16)h;
      sh_ph[r][hh] = h;
      encg[((size_t)(r0 + r) * SEQ + s) * NH + hh] = (h16)h;
      if (hh < NF && s + 1 < SEQ) sh_hx[r][hh] = (h16)xnext[rr];
    }
    __syncthreads();
  }

  // preload dec B fragments (after encoder: enc frags die, regs reused)
  h16x8 bfD[4][8];
  float bD[4];
  #pragma unroll
  for (int nt = 0; nt < 4; ++nt) {
    int n = w * 64 + nt * 16 + ln;
    bD[nt] = bdecp[n];
    #pragma unroll
    for (int kt = 0; kt < 8; ++kt)
      bfD[nt][kt] = *(const h16x8*)(w16dec + n * KD + kt * 32 + lq * 8);
  }

  // decoder init
  #pragma unroll
  for (int rr = 0; rr < 2; ++rr) {
    int r = rq * 2 + rr;
    h16 hv = sh_hx[r][8 + hh];
    sh_cath[r][128 + hh] = hv;
    sh_ainh[r][hh] = hv;
  }
  if (t < 56) {
    int r = t / 7, f = t - (t / 7) * 7;
    sh_ainh[r][128 + f] = (h16)xb[((size_t)(r0 + r) * SEQ + (SEQ - 1)) * NF + f];  // y0
  }
  if (t < ROWS) sh_ainh[t][135] = (h16)0.f;
  __syncthreads();

  // decoder per-thread constants
  const int ss = t % 168;
  const int rh = t / 168;
  const float batt = (t < 336) ? b_att[ss] : 0.f;
  const int sl = t & 31;
  const int sr = t >> 5;
  const int cr = t >> 6;             // D3 row (all lanes of a wave share)
  const int o  = t & 15;             // D3 h-octet
  const int q4 = (t >> 4) & 3;       // D3 s-quadrant
  const int orow = t / 7;
  const int ocol = t - (t / 7) * 7;

  // ================= decoder: 96 steps =================
  for (int p = 0; p < NP; ++p) {
    // D1: logits = attn_in . W_att[s] + b_att[s]
    if (t < 336) {
      float a0 = batt, a1 = batt, a2 = batt, a3 = batt;
      const h16* war = watt + ss * 136;
      #pragma unroll 2
      for (int jq = 0; jq < 34; ++jq) {
        uint2 wv = *(const uint2*)(war + jq * 4);
        h16x2 w0 = bc2(wv.x), w1 = bc2(wv.y);
        uint2 v0 = *(const uint2*)&sh_ainh[rh * 4 + 0][jq * 4];
        uint2 v1 = *(const uint2*)&sh_ainh[rh * 4 + 1][jq * 4];
        uint2 v2 = *(const uint2*)&sh_ainh[rh * 4 + 2][jq * 4];
        uint2 v3 = *(const uint2*)&sh_ainh[rh * 4 + 3][jq * 4];
        a0 = fdot2f(bc2(v0.x), w0, a0); a0 = fdot2f(bc2(v0.y), w1, a0);
        a1 = fdot2f(bc2(v1.x), w0, a1); a1 = fdot2f(bc2(v1.y), w1, a1);
        a2 = fdot2f(bc2(v2.x), w0, a2); a2 = fdot2f(bc2(v2.y), w1, a2);
        a3 = fdot2f(bc2(v3.x), w0, a3); a3 = fdot2f(bc2(v3.y), w1, a3);
      }
      sh_attw[rh * 4 + 0][ss] = a0;
      sh_attw[rh * 4 + 1][ss] = a1;
      sh_attw[rh * 4 + 2][ss] = a2;
      sh_attw[rh * 4 + 3][ss] = a3;
    }
    __syncthreads();

    // D2: softmax over s
    if (t < 256) {
      float vals[6];
      float m = -1e30f;
      #pragma unroll
      for (int j = 0; j < 6; ++j) {
        int s = sl + 32 * j;
        vals[j] = (s < SEQ) ? sh_attw[sr][s] : -1e30f;
        m = fmaxf(m, vals[j]);
      }
      #pragma unroll
      for (int off = 16; off > 0; off >>= 1) m = fmaxf(m, __shfl_xor(m, off, 32));
      float sum = 0.f;
      #pragma unroll
      for (int j = 0; j < 6; ++j) {
        float e = __expf(vals[j] - m);
        e = (sl + 32 * j < SEQ) ? e : 0.f;
        vals[j] = e;
        sum += e;
      }
      #pragma unroll
      for (int off = 16; off > 0; off >>= 1) sum += __shfl_xor(sum, off, 32);
      float inv = 1.f / sum;
      #pragma unroll
      for (int j = 0; j < 6; ++j) {
        int s = sl + 32 * j;
        if (s < SEQ) sh_attw[sr][s] = vals[j] * inv;
      }
    }
    __syncthreads();

    // D3: combine[r][h] = sum_s w[r][s]*enc[r][s][h] — 16B loads, 4-way s-split + shfl reduce
    {
      const h16* er = encg + ((size_t)(r0 + cr) * SEQ) * NH + o * 8;
      float a[8] = {0.f, 0.f, 0.f, 0.f, 0.f, 0.f, 0.f, 0.f};
      const int sbeg = q4 * 42;
      #pragma unroll 2
      for (int si = 0; si < 42; ++si) {
        int s = sbeg + si;
        float wg = sh_attw[cr][s];
        h16x8 e = *(const h16x8*)(er + (size_t)s * NH);
        #pragma unroll
        for (int j = 0; j < 8; ++j) a[j] += wg * (float)e[j];
      }
      #pragma unroll
      for (int j = 0; j < 8; ++j) { a[j] += __shfl_xor(a[j], 16); a[j] += __shfl_xor(a[j], 32); }
      if (q4 == 0) {
        h16x8 cv;
        #pragma unroll
        for (int j = 0; j < 8; ++j) cv[j] = (h16)a[j];
        *(h16x8*)(&sh_cath[cr][o * 8]) = cv;
      }
    }
    __syncthreads();

    // D4: gates = [combine|prev_h] @ W_dec^T via MFMA (K=256)
    {
      h16x8 af[8];
      #pragma unroll
      for (int kt = 0; kt < 8; ++kt)
        af[kt] = *(const h16x8*)(&sh_cath[ln][kt * 32 + lq * 8]);
      #pragma unroll
      for (int nt = 0; nt < 4; ++nt) {
        f32x4 acc = {0.f, 0.f, 0.f, 0.f};
        #pragma unroll
        for (int kt = 0; kt < 8; ++kt)
          acc = __builtin_amdgcn_mfma_f32_16x16x32_f16(af[kt], bfD[nt][kt], acc, 0, 0, 0);
        int n = w * 64 + nt * 16 + ln;
        #pragma unroll
        for (int reg = 0; reg < 4; ++reg) {
          int m = lq * 4 + reg;
          if (m < ROWS) sh_pre[m][n] = acc[reg] + bD[nt];
        }
      }
    }
    __syncthreads();

    // D5: c_new = sigm(f)*prev_h + sigm(i)*tanh(g)
    #pragma unroll
    for (int rr = 0; rr < 2; ++rr) {
      int r = rq * 2 + rr;
      float gi = sigm(sh_pre[r][hh]);
      float gf = sigm(sh_pre[r][hh + 128]);
      float gg = tanh_(sh_pre[r][hh + 256]);
      float cn = gf * sh_ph[r][hh] + gi * gg;
      sh_ph[r][hh] = cn;
      h16 ch = (h16)cn;
      sh_cath[r][128 + hh] = ch;  // prev_h for next D4
      sh_ainh[r][hh] = ch;        // attn_in for next D1
    }
    __syncthreads();

    // D6: out[r][f] = c_new . W_out[f] + b_out[f]
    if (t < 56) {
      float a = bout[ocol];
      const float* wr = Wout + ocol * NH;
      #pragma unroll 8
      for (int k = 0; k < NH; k += 4) {
        float4 pv = *(const float4*)&sh_ph[orow][k];
        float4 wv = *(const float4*)(wr + k);
        a += pv.x * wv.x + pv.y * wv.y + pv.z * wv.z + pv.w * wv.w;
      }
      sh_out[orow][ocol] = a;
      sh_ainh[orow][128 + ocol] = (h16)a;  // y_prev for next D1
    }
    __syncthreads();

    // D7: final[b][p] = out . W_fin + b_fin
    if (t < ROWS) {
      float a = bfin[0];
      #pragma unroll
      for (int f = 0; f < NF; ++f) a += sh_out[t][f] * Wfin[f];
      out[(size_t)(r0 + t) * NP + p] = a;
    }
  }
}

extern "C" void kernel_launch(void* const* d_in, const int* in_sizes, int n_in,
                              void* d_out, int out_size, void* d_ws, size_t ws_size,
                              hipStream_t stream) {
  const float* xb      = (const float*)d_in[0];
  const float* Wih_enc = (const float*)d_in[1];
  const float* Whh_enc = (const float*)d_in[2];
  const float* bih_enc = (const float*)d_in[3];
  const float* bhh_enc = (const float*)d_in[4];
  const float* Watt    = (const float*)d_in[5];
  const float* batt    = (const float*)d_in[6];
  const float* Wih_dec = (const float*)d_in[7];
  const float* Whh_dec = (const float*)d_in[8];
  const float* bih_dec = (const float*)d_in[9];
  const float* bhh_dec = (const float*)d_in[10];
  const float* Wout    = (const float*)d_in[11];
  const float* bout    = (const float*)d_in[12];
  const float* Wfin    = (const float*)d_in[13];
  const float* bfin    = (const float*)d_in[14];
  char* ws = (char*)d_ws;  // needs ~88.6 MB

  // 81920 + 131072 + 22848 + 512 = 236352 elements
  setup_weights<<<924, 256, 0, stream>>>(Wih_enc, Whh_enc, Wih_dec, Whh_dec, Watt,
                                         bih_enc, bhh_enc, bih_dec, bhh_dec, ws);
  encdec_kernel<<<NB / ROWS, NTHR, 0, stream>>>(
      xb, batt, Wout, bout, Wfin, bfin,
      (const h16*)(ws + WENC_OFF), (const h16*)(ws + WDEC_OFF),
      (const h16*)(ws + WATT_OFF), (const float*)(ws + BENC_OFF),
      (const float*)(ws + BDEC_OFF), (h16*)(ws + ENC_OFF),
      (float*)d_out);
}

// Round 4
// 1493.842 us; speedup vs baseline: 2.5114x; 1.4099x over previous
//
#include <hip/hip_runtime.h>
#include <hip/hip_fp8.h>

// Problem constants
#define NB   2048   // batch
#define SEQ  168    // encoder steps
#define NF   7      // features
#define NH   128    // hidden
#define G4   512    // 4*NH gate rows
#define NP   96     // decoder steps
#define ROWS 8      // batch rows per block (padded to M=16 for MFMA)
#define NTHR 512
#define KE   160    // enc A/B K: [x 0..6][pad 7][h 8..135][pad 136..159]
#define KD   256    // dec A/B K: [combine 0..127][prev_h 128..255]
#define KA   160    // att A/B K: [h 0..127][y 128..134][pad 135..159]
#define HXS  168    // h16 row stride for MFMA-A tiles (336B -> 2-way banks, free)
#define CTS  264    // sh_cath row stride in h16 (528B -> 2-way)
#define PRS  513    // sh_pre row stride in f32

typedef _Float16 h16;
typedef _Float16 h16x2 __attribute__((ext_vector_type(2)));
typedef _Float16 h16x8 __attribute__((ext_vector_type(8)));
typedef float    f32x2 __attribute__((ext_vector_type(2)));
typedef float    f32x4 __attribute__((ext_vector_type(4)));
typedef unsigned int u32x4 __attribute__((ext_vector_type(4)));

// -------- d_ws layout (bytes). Total ~44.6 MB. --------
constexpr size_t WENC_OFF = 0;        // h16[512][160]
constexpr size_t WDEC_OFF = 163840;   // h16[512][256]
constexpr size_t WATT_OFF = 425984;   // h16[168][160]  [h|y|0-pad]
constexpr size_t BENC_OFF = 479744;   // f32[512]
constexpr size_t BDEC_OFF = 481792;   // f32[512]
constexpr size_t ENC_OFF  = 524288;   // fp8[NB*SEQ*NH] encoder outputs (44 MB), scaled x16

__device__ __forceinline__ float sigm(float x) { return 1.f / (1.f + __expf(-x)); }
__device__ __forceinline__ float tanh_(float x) {
  float e = __expf(-2.f * fabsf(x));
  return copysignf((1.f - e) / (1.f + e), x);
}

// force a preloaded fragment to stay register-resident (opaque def kills remat)
__device__ __forceinline__ void keepreg(h16x8& v) {
  u32x4& u = reinterpret_cast<u32x4&>(v);
  asm volatile("" : "+v"(u));
}
__device__ __forceinline__ void keepreg(float& v) { asm volatile("" : "+v"(v)); }

// fp8 e4m3 pack/unpack (HW cvt on gfx950; self-consistent either path)
__device__ __forceinline__ unsigned char pack_fp8(float x) {
#if __has_builtin(__builtin_amdgcn_cvt_pk_fp8_f32)
  int v = __builtin_amdgcn_cvt_pk_fp8_f32(x, 0.f, 0, false);
  return (unsigned char)(v & 0xff);
#else
  __hip_fp8_e4m3 q(x);
  return *(unsigned char*)&q;
#endif
}
template <bool HI>
__device__ __forceinline__ f32x2 unp2(unsigned int w) {
#if __has_builtin(__builtin_amdgcn_cvt_pk_f32_fp8)
  return __builtin_amdgcn_cvt_pk_f32_fp8(w, HI);   // HI is a constant here
#else
  __hip_fp8_e4m3 a, b;
  constexpr unsigned int sh = HI ? 16 : 0;
  *(unsigned char*)&a = (w >> sh) & 0xff;
  *(unsigned char*)&b = (w >> (sh + 8)) & 0xff;
  f32x2 r; r.x = (float)a; r.y = (float)b; return r;
#endif
}

// -------- setup: cast/pack weights into ws --------
__global__ void setup_weights(const float* __restrict__ Wih_enc, const float* __restrict__ Whh_enc,
                              const float* __restrict__ Wih_dec, const float* __restrict__ Whh_dec,
                              const float* __restrict__ Watt,
                              const float* __restrict__ bihe, const float* __restrict__ bhhe,
                              const float* __restrict__ bihd, const float* __restrict__ bhhd,
                              char* __restrict__ ws) {
  int idx = blockIdx.x * blockDim.x + threadIdx.x;
  if (idx < 81920) {
    int n = idx / KE, k = idx % KE;
    float v = 0.f;
    if (k < NF) v = Wih_enc[n * NF + k];
    else if (k >= 8 && k < 136) v = Whh_enc[n * NH + (k - 8)];
    ((h16*)(ws + WENC_OFF))[idx] = (h16)v;
  } else if (idx < 81920 + 131072) {
    int i = idx - 81920;
    int n = i / KD, k = i % KD;
    float v = (k < NH) ? Wih_dec[n * NH + k] : Whh_dec[n * NH + (k - NH)];
    ((h16*)(ws + WDEC_OFF))[i] = (h16)v;
  } else if (idx < 81920 + 131072 + 26880) {
    int i = idx - (81920 + 131072);
    int k = i % KA, s = i / KA;
    float v = (k < NH + NF) ? Watt[s * (NH + NF) + k] : 0.f;
    ((h16*)(ws + WATT_OFF))[i] = (h16)v;
  } else if (idx < 81920 + 131072 + 26880 + 512) {
    int g = idx - (81920 + 131072 + 26880);
    ((float*)(ws + BENC_OFF))[g] = bihe[g] + bhhe[g];
    ((float*)(ws + BDEC_OFF))[g] = bihd[g] + bhhd[g];
  }
}

// -------- main persistent kernel --------
__global__ __launch_bounds__(NTHR, 2)
void encdec_kernel(const float* __restrict__ xb, const float* __restrict__ b_att,
                   const float* __restrict__ Wout, const float* __restrict__ bout,
                   const float* __restrict__ Wfin, const float* __restrict__ bfin,
                   const h16* __restrict__ w16enc, const h16* __restrict__ w16dec,
                   const h16* __restrict__ watt, const float* __restrict__ bencp,
                   const float* __restrict__ bdecp, unsigned char* __restrict__ enc8,
                   float* __restrict__ out) {
  __shared__ alignas(16) h16   sh_hx[16][HXS];      // MFMA A (enc)                   5376 B
  __shared__ alignas(16) float sh_c[ROWS][NH];      //                                4096 B
  __shared__ alignas(16) float sh_pre[ROWS][PRS];   //                               16416 B
  __shared__ alignas(16) float sh_ph[ROWS][NH];     //                                4096 B
  __shared__ alignas(16) h16   sh_ainh[16][HXS];    // MFMA A (att): [h|y|0]          5376 B
  __shared__ alignas(16) h16   sh_cath[16][CTS];    // MFMA A (dec): [combine|prev_h] 8448 B
  __shared__ alignas(16) float sh_attw[ROWS][SEQ];  //                                5376 B
  __shared__ alignas(16) float sh_out[ROWS][8];     //                                 256 B
  __shared__ alignas(16) h16   sh_watt2[40][HXS];   // W_att rows 128..167           13440 B
  // total ~62.9 KB static

  const int t  = threadIdx.x;
  const int r0 = blockIdx.x * ROWS;

  // init LDS
  for (int i = t; i < 16 * HXS; i += NTHR) {
    int r = i / HXS, k = i % HXS;
    float v = 0.f;
    if (r < ROWS && k < NF) v = xb[((size_t)(r0 + r) * SEQ + 0) * NF + k];
    sh_hx[r][k] = (h16)v;
    sh_ainh[r][k] = (h16)0.f;   // covers k-pad and rows 8-15
  }
  for (int i = t; i < ROWS * NH; i += NTHR) { int r = i >> 7, k = i & 127; sh_c[r][k] = 0.f; }
  for (int i = t; i < 8 * CTS; i += NTHR)  { int r = i / CTS, k = i % CTS; sh_cath[8 + r][k] = (h16)0.f; }
  for (int i = t; i < 40 * KA; i += NTHR)  { int r = i / KA, k = i % KA; sh_watt2[r][k] = watt[(128 + r) * KA + k]; }

  // wave/lane decomposition for MFMA
  const int w  = t >> 6;   // wave id
  const int l  = t & 63;
  const int lq = l >> 4;
  const int ln = l & 15;

  // preload enc B fragments -> VGPRs (pinned)
  h16x8 bfE[4][5];
  float bE[4];
  #pragma unroll
  for (int nt = 0; nt < 4; ++nt) {
    int n = w * 64 + nt * 16 + ln;
    bE[nt] = bencp[n];
    keepreg(bE[nt]);
    #pragma unroll
    for (int kt = 0; kt < 5; ++kt) {
      bfE[nt][kt] = *(const h16x8*)(w16enc + n * KE + kt * 32 + lq * 8);
      keepreg(bfE[nt][kt]);
    }
  }

  const int hh = t & 127;
  const int rq = t >> 7;

  __syncthreads();

  // ================= encoder: 168 steps =================
  for (int s = 0; s < SEQ; ++s) {
    float xnext[2];
    #pragma unroll
    for (int rr = 0; rr < 2; ++rr) {
      int r = rq * 2 + rr;
      xnext[rr] = (hh < NF && s + 1 < SEQ) ? xb[((size_t)(r0 + r) * SEQ + s + 1) * NF + hh] : 0.f;
    }

    // E1: pre = [x|h] @ W_enc^T via MFMA
    {
      h16x8 af[5];
      #pragma unroll
      for (int kt = 0; kt < 5; ++kt)
        af[kt] = *(const h16x8*)(&sh_hx[ln][kt * 32 + lq * 8]);
      #pragma unroll
      for (int nt = 0; nt < 4; ++nt) {
        f32x4 acc = {0.f, 0.f, 0.f, 0.f};
        #pragma unroll
        for (int kt = 0; kt < 5; ++kt)
          acc = __builtin_amdgcn_mfma_f32_16x16x32_f16(af[kt], bfE[nt][kt], acc, 0, 0, 0);
        int n = w * 64 + nt * 16 + ln;
        #pragma unroll
        for (int reg = 0; reg < 4; ++reg) {
          int m = lq * 4 + reg;
          if (m < ROWS) sh_pre[m][n] = acc[reg] + bE[nt];
        }
      }
    }
    __syncthreads();

    // E2: LSTM cell elementwise; h history stored as fp8 e4m3 scaled x16
    #pragma unroll
    for (int rr = 0; rr < 2; ++rr) {
      int r = rq * 2 + rr;
      float gi = sigm(sh_pre[r][hh]);
      float gf = sigm(sh_pre[r][hh + 128]);
      float gg = tanh_(sh_pre[r][hh + 256]);
      float go = sigm(sh_pre[r][hh + 384]);
      float c = gf * sh_c[r][hh] + gi * gg;
      float h = go * tanh_(c);
      sh_c[r][hh] = c;
      sh_hx[r][8 + hh] = (h16)h;
      sh_ph[r][hh] = h;
      enc8[((size_t)(r0 + r) * SEQ + s) * NH + hh] = pack_fp8(h * 16.f);
      if (hh < NF && s + 1 < SEQ) sh_hx[r][hh] = (h16)xnext[rr];
    }
    __syncthreads();
  }

  // preload dec + att B fragments (enc frags dead -> regs reuse), pinned
  h16x8 bfD[4][8];
  float bD[4];
  #pragma unroll
  for (int nt = 0; nt < 4; ++nt) {
    int n = w * 64 + nt * 16 + ln;
    bD[nt] = bdecp[n];
    keepreg(bD[nt]);
    #pragma unroll
    for (int kt = 0; kt < 8; ++kt) {
      bfD[nt][kt] = *(const h16x8*)(w16dec + n * KD + kt * 32 + lq * 8);
      keepreg(bfD[nt][kt]);
    }
  }
  h16x8 bfA[5];          // W_att tile w (s = w*16+ln), register-resident
  {
    int sA = w * 16 + ln;   // < 128
    #pragma unroll
    for (int kt = 0; kt < 5; ++kt) {
      bfA[kt] = *(const h16x8*)(watt + sA * KA + kt * 32 + lq * 8);
      keepreg(bfA[kt]);
    }
  }
  float battR = b_att[w * 16 + ln];
  keepreg(battR);
  const int s2 = 128 + w * 16 + ln;            // second att tile (waves 0-2)
  float batt2 = (w < 3 && s2 < SEQ) ? b_att[s2] : 0.f;
  keepreg(batt2);

  // decoder init
  #pragma unroll
  for (int rr = 0; rr < 2; ++rr) {
    int r = rq * 2 + rr;
    h16 hv = sh_hx[r][8 + hh];
    sh_cath[r][128 + hh] = hv;
    sh_ainh[r][hh] = hv;
  }
  if (t < 56) {
    int r = t / 7, f = t - (t / 7) * 7;
    sh_ainh[r][128 + f] = (h16)xb[((size_t)(r0 + r) * SEQ + (SEQ - 1)) * NF + f];  // y0
  }
  __syncthreads();

  // decoder per-thread constants
  const int sl = t & 31;
  const int sr = t >> 5;
  const int cr = t >> 6;             // D3 row
  const int o  = t & 15;             // D3 h-octet
  const int q4 = (t >> 4) & 3;       // D3 s-quadrant
  const int orow = t / 7;
  const int ocol = t - (t / 7) * 7;

  // ================= decoder: 96 steps =================
  for (int p = 0; p < NP; ++p) {
    // D1: logits = attn_in @ W_att^T via MFMA (M=16, N=168, K=160)
    {
      h16x8 afA[5];
      #pragma unroll
      for (int kt = 0; kt < 5; ++kt)
        afA[kt] = *(const h16x8*)(&sh_ainh[ln][kt * 32 + lq * 8]);
      f32x4 acc = {0.f, 0.f, 0.f, 0.f};
      #pragma unroll
      for (int kt = 0; kt < 5; ++kt)
        acc = __builtin_amdgcn_mfma_f32_16x16x32_f16(afA[kt], bfA[kt], acc, 0, 0, 0);
      int s1 = w * 16 + ln;
      #pragma unroll
      for (int reg = 0; reg < 4; ++reg) {
        int m = lq * 4 + reg;
        if (m < ROWS) sh_attw[m][s1] = acc[reg] + battR;
      }
      if (w < 3) {   // tiles 8-10 (s in [128,168)); B frags from LDS
        int srow = (s2 < SEQ ? s2 : SEQ - 1) - 128;
        f32x4 acc2 = {0.f, 0.f, 0.f, 0.f};
        #pragma unroll
        for (int kt = 0; kt < 5; ++kt) {
          h16x8 bf2 = *(const h16x8*)(&sh_watt2[srow][kt * 32 + lq * 8]);
          acc2 = __builtin_amdgcn_mfma_f32_16x16x32_f16(afA[kt], bf2, acc2, 0, 0, 0);
        }
        if (s2 < SEQ) {
          #pragma unroll
          for (int reg = 0; reg < 4; ++reg) {
            int m = lq * 4 + reg;
            if (m < ROWS) sh_attw[m][s2] = acc2[reg] + batt2;
          }
        }
      }
    }
    __syncthreads();

    // D2: softmax over s
    if (t < 256) {
      float vals[6];
      float m = -1e30f;
      #pragma unroll
      for (int j = 0; j < 6; ++j) {
        int s = sl + 32 * j;
        vals[j] = (s < SEQ) ? sh_attw[sr][s] : -1e30f;
        m = fmaxf(m, vals[j]);
      }
      #pragma unroll
      for (int off = 16; off > 0; off >>= 1) m = fmaxf(m, __shfl_xor(m, off, 32));
      float sum = 0.f;
      #pragma unroll
      for (int j = 0; j < 6; ++j) {
        float e = __expf(vals[j] - m);
        e = (sl + 32 * j < SEQ) ? e : 0.f;
        vals[j] = e;
        sum += e;
      }
      #pragma unroll
      for (int off = 16; off > 0; off >>= 1) sum += __shfl_xor(sum, off, 32);
      float inv = 1.f / sum;
      #pragma unroll
      for (int j = 0; j < 6; ++j) {
        int s = sl + 32 * j;
        if (s < SEQ) sh_attw[sr][s] = vals[j] * inv;
      }
    }
    __syncthreads();

    // D3: combine[r][h] = sum_s w[r][s]*enc8[r][s][h] (fp8, x16-scaled)
    {
      const unsigned char* er = enc8 + ((size_t)(r0 + cr) * SEQ) * NH + o * 8;
      float a[8] = {0.f, 0.f, 0.f, 0.f, 0.f, 0.f, 0.f, 0.f};
      const int sbeg = q4 * 42;
      #pragma unroll 3
      for (int si = 0; si < 42; ++si) {
        int s = sbeg + si;
        float wg = sh_attw[cr][s];
        uint2 ev = *(const uint2*)(er + (size_t)s * NH);
        f32x2 p0 = unp2<false>(ev.x);
        f32x2 p1 = unp2<true>(ev.x);
        f32x2 p2 = unp2<false>(ev.y);
        f32x2 p3 = unp2<true>(ev.y);
        a[0] += wg * p0.x; a[1] += wg * p0.y;
        a[2] += wg * p1.x; a[3] += wg * p1.y;
        a[4] += wg * p2.x; a[5] += wg * p2.y;
        a[6] += wg * p3.x; a[7] += wg * p3.y;
      }
      #pragma unroll
      for (int j = 0; j < 8; ++j) { a[j] += __shfl_xor(a[j], 16); a[j] += __shfl_xor(a[j], 32); }
      if (q4 == 0) {
        h16x8 cv;
        #pragma unroll
        for (int j = 0; j < 8; ++j) cv[j] = (h16)(a[j] * 0.0625f);  // /16 scale
        *(h16x8*)(&sh_cath[cr][o * 8]) = cv;
      }
    }
    __syncthreads();

    // D4: gates = [combine|prev_h] @ W_dec^T via MFMA (K=256)
    {
      h16x8 af[8];
      #pragma unroll
      for (int kt = 0; kt < 8; ++kt)
        af[kt] = *(const h16x8*)(&sh_cath[ln][kt * 32 + lq * 8]);
      #pragma unroll
      for (int nt = 0; nt < 4; ++nt) {
        f32x4 acc = {0.f, 0.f, 0.f, 0.f};
        #pragma unroll
        for (int kt = 0; kt < 8; ++kt)
          acc = __builtin_amdgcn_mfma_f32_16x16x32_f16(af[kt], bfD[nt][kt], acc, 0, 0, 0);
        int n = w * 64 + nt * 16 + ln;
        #pragma unroll
        for (int reg = 0; reg < 4; ++reg) {
          int m = lq * 4 + reg;
          if (m < ROWS) sh_pre[m][n] = acc[reg] + bD[nt];
        }
      }
    }
    __syncthreads();

    // D5: c_new = sigm(f)*prev_h + sigm(i)*tanh(g)
    #pragma unroll
    for (int rr = 0; rr < 2; ++rr) {
      int r = rq * 2 + rr;
      float gi = sigm(sh_pre[r][hh]);
      float gf = sigm(sh_pre[r][hh + 128]);
      float gg = tanh_(sh_pre[r][hh + 256]);
      float cn = gf * sh_ph[r][hh] + gi * gg;
      sh_ph[r][hh] = cn;
      h16 ch = (h16)cn;
      sh_cath[r][128 + hh] = ch;  // prev_h for next D4
      sh_ainh[r][hh] = ch;        // attn_in for next D1
    }
    __syncthreads();

    // D6: out[r][f] = c_new . W_out[f] + b_out[f]
    if (t < 56) {
      float a = bout[ocol];
      const float* wr = Wout + ocol * NH;
      #pragma unroll 8
      for (int k = 0; k < NH; k += 4) {
        float4 pv = *(const float4*)&sh_ph[orow][k];
        float4 wv = *(const float4*)(wr + k);
        a += pv.x * wv.x + pv.y * wv.y + pv.z * wv.z + pv.w * wv.w;
      }
      sh_out[orow][ocol] = a;
      sh_ainh[orow][128 + ocol] = (h16)a;  // y_prev for next D1
    }
    __syncthreads();

    // D7: final[b][p] = out . W_fin + b_fin
    if (t < ROWS) {
      float a = bfin[0];
      #pragma unroll
      for (int f = 0; f < NF; ++f) a += sh_out[t][f] * Wfin[f];
      out[(size_t)(r0 + t) * NP + p] = a;
    }
  }
}

extern "C" void kernel_launch(void* const* d_in, const int* in_sizes, int n_in,
                              void* d_out, int out_size, void* d_ws, size_t ws_size,
                              hipStream_t stream) {
  const float* xb      = (const float*)d_in[0];
  const float* Wih_enc = (const float*)d_in[1];
  const float* Whh_enc = (const float*)d_in[2];
  const float* bih_enc = (const float*)d_in[3];
  const float* bhh_enc = (const float*)d_in[4];
  const float* Watt    = (const float*)d_in[5];
  const float* batt    = (const float*)d_in[6];
  const float* Wih_dec = (const float*)d_in[7];
  const float* Whh_dec = (const float*)d_in[8];
  const float* bih_dec = (const float*)d_in[9];
  const float* bhh_dec = (const float*)d_in[10];
  const float* Wout    = (const float*)d_in[11];
  const float* bout    = (const float*)d_in[12];
  const float* Wfin    = (const float*)d_in[13];
  const float* bfin    = (const float*)d_in[14];
  char* ws = (char*)d_ws;  // needs ~44.6 MB

  // 81920 + 131072 + 26880 + 512 = 240384 elements = 939 * 256
  setup_weights<<<939, 256, 0, stream>>>(Wih_enc, Whh_enc, Wih_dec, Whh_dec, Watt,
                                         bih_enc, bhh_enc, bih_dec, bhh_dec, ws);
  encdec_kernel<<<NB / ROWS, NTHR, 0, stream>>>(
      xb, batt, Wout, bout, Wfin, bfin,
      (const h16*)(ws + WENC_OFF), (const h16*)(ws + WDEC_OFF),
      (const h16*)(ws + WATT_OFF), (const float*)(ws + BENC_OFF),
      (const float*)(ws + BDEC_OFF), (unsigned char*)(ws + ENC_OFF),
      (float*)d_out);
}